// Round 5
// baseline (1047.131 us; speedup 1.0000x reference)
//
#include <hip/hip_runtime.h>

// Soft-Blake2 cipher: 2e6 rows x 16 f32 -> 2e6 x 8 f32.
// R9: numerics bit-identical to R5-R8 per element (absmax 0.0078125),
// mechanically widened v2f -> v4f: 4 rows/thread = two interleaved
// packed streams -> explicit ILP=2 inside every (serial) sigmoid chain.
//   Evidence trail:
//   - R5(blk256)/R7(blk128)/R8(blk128,bounds(128,4)): all ~933-950us,
//     VALUBusy ~88%, Occ ~41%, VGPR 56. Launch config is a dead lever;
//     allocator chooses 56 VGPR even with a 128-reg budget.
//   - R6 (bounds(128,8) -> VGPR 32): spilled to scratch (FETCH/WRITE
//     +330MB), dur 973. Tight caps fail.
//   - Issue model (calibrated): per-wave busy = 43.7k full-rate +
//     5120 trans x ~16cy = ~126k cy; wall 147k -> ~12% idle = trans
//     dependency shadows uncovered at 3.3 waves/SIMD with serial
//     per-chain scheduling (VGPR 56 < the 64 needed for full state
//     residency => compiler is scheduling tight, low ILP).
//   - Fix: double per-wave independent work instead of wave count.
//     4 rows/thread: same total issue work, half the waves, 2x ready
//     ops per stall window, half the prologue/loop overhead.
//   Register budget: m 64 + state 64 + temps ~20 => ~150 VGPR.
//   __launch_bounds__(128,3) caps at 170 (prevents 2-wave cliff);
//   demand < cap => no spills. Tripwire: FETCH/WRITE >> 62.5MB = spill.
// R3 lesson stands: ANY 1-ulp sigmoid change fails. Do not touch math.

#pragma clang fp contract(off)  // mul/add must round separately, like numpy

typedef float v4f __attribute__((ext_vector_type(4)));

// IV = float32(uint64) * 2^-64, matching np.asarray(ints, float32)/2.0**64.
#define IV0 ((float)7640891576956012808ULL * 0x1p-64f)
#define IV1 ((float)13503953896175478587ULL * 0x1p-64f)
#define IV2 ((float)4354685564936845355ULL * 0x1p-64f)
#define IV3 ((float)11912009170470909681ULL * 0x1p-64f)
#define IV4 ((float)5840696475078001361ULL * 0x1p-64f)
#define IV5 ((float)11170449401992604703ULL * 0x1p-64f)
#define IV6 ((float)2270897969802886507ULL * 0x1p-64f)
#define IV7 ((float)6620516959819538809ULL * 0x1p-64f)

// log2(e) split: HI = float(log2 e), LO = log2(e) - (double)HI.
#define L2E_HI 0x1.715476p+0f
#define L2E_LO 1.9259630e-8f
// 1.5 * 2^23: RNE magic. t + MAGIC is integer-valued with bits
// 0x4B400000 + rint(t) for |t| < 2^22.
#define RNE_MAGIC 12582912.0f

static __device__ __forceinline__ v4f sp(float x) { return (v4f){x, x, x, x}; }
static __device__ __forceinline__ v4f vfma(v4f a, v4f b, v4f c) {
    return __builtin_elementwise_fma(a, b, c);
}
static __device__ __forceinline__ v4f vfract(v4f a) {
    v4f r;
    r.x = __builtin_amdgcn_fractf(a.x);  // v_fract_f32 = S0 - floor(S0)
    r.y = __builtin_amdgcn_fractf(a.y);
    r.z = __builtin_amdgcn_fractf(a.z);
    r.w = __builtin_amdgcn_fractf(a.w);
    return r;
}

// sigmoid(z) = 1/(1+e^-z). Bit-identical per element to R2/R4/R5:
//   n = rint(w*L2E_HI)  [via RNE magic add]
//   f = fma(w,HI,-n) + w*LO   (exact residual, 2 fma)
//   e = v_exp_f32(f)          (|f| <= 0.5)
//   sc = 2^n bit-constructed from the magic sum's bit pattern (exact:
//        low 9 bits of 0x4B400000 are zero, so (bits<<23)+0x3F800000
//        == (n+127)<<23 mod 2^32)
//   d = fma(e, sc, 1.0)       (product exact, one rounding)
//   rcp + 1 Newton step       (~0.5-1 ulp)
static __device__ __forceinline__ v4f sigf4(v4f z) {
    v4f w = -z;
    v4f t = w * L2E_HI;                        // 2x pk_mul
    v4f tmp = t + sp(RNE_MAGIC);               // 2x pk_add
    v4f n = tmp - sp(RNE_MAGIC);               // 2x pk_add (exact)
    v4f f = vfma(w, sp(L2E_HI), -n);           // 2x pk_fma (exact residual)
    f = vfma(w, sp(L2E_LO), f);                // 2x pk_fma
    v4f e;
    e.x = __builtin_amdgcn_exp2f(f.x);         // 4x v_exp_f32 (trans)
    e.y = __builtin_amdgcn_exp2f(f.y);
    e.z = __builtin_amdgcn_exp2f(f.z);
    e.w = __builtin_amdgcn_exp2f(f.w);
    v4f sc;                                    // 2^n exact: (n+127)<<23
    sc.x = __uint_as_float((__float_as_uint(tmp.x) << 23) + 0x3F800000u);
    sc.y = __uint_as_float((__float_as_uint(tmp.y) << 23) + 0x3F800000u);
    sc.z = __uint_as_float((__float_as_uint(tmp.z) << 23) + 0x3F800000u);
    sc.w = __uint_as_float((__float_as_uint(tmp.w) << 23) + 0x3F800000u);
    v4f d = vfma(e, sc, sp(1.0f));             // 2x pk_fma, one rounding
    v4f q0;
    q0.x = __builtin_amdgcn_rcpf(d.x);         // 4x v_rcp_f32 (trans)
    q0.y = __builtin_amdgcn_rcpf(d.y);
    q0.z = __builtin_amdgcn_rcpf(d.z);
    q0.w = __builtin_amdgcn_rcpf(d.w);
    v4f err = vfma(-d, q0, sp(1.0f));          // 2x pk_fma
    return vfma(q0, err, q0);                  // 2x pk_fma
}

static __device__ __forceinline__ v4f soft_add4(v4f x, v4f y) {
    v4f s = x + y;
    v4f w = sigf4(10.0f * (s - 1.0f));         // sub then mul, ref order
    return s - w;
}

static __device__ __forceinline__ v4f soft_xor4(v4f x, v4f y) {
    v4f xs = sigf4(10.0f * (x - 0.5f));
    v4f ys = sigf4(10.0f * (y - 0.5f));
    v4f t1 = xs * (1.0f - ys);
    v4f t2 = (1.0f - xs) * ys;
    v4f r = (t1 + t2) - t1 * t2;               // contraction off
    r.x = __builtin_amdgcn_fmed3f(r.x, 0.0f, 1.0f);  // clamp, 1 op/elem
    r.y = __builtin_amdgcn_fmed3f(r.y, 0.0f, 1.0f);
    r.z = __builtin_amdgcn_fmed3f(r.z, 0.0f, 1.0f);
    r.w = __builtin_amdgcn_fmed3f(r.w, 0.0f, 1.0f);
    return r;
}

// rotate_right, bit-identical to the reference mod-2^64 chain (exact pow2
// scales; fract exact; the single rounding lands at the same mantissa
// position as the reference's sr+sl add). v_fract == sub-floor here:
// inputs are clamped soft_xor outputs in [0,1] (rotr only ever follows
// soft_xor in G), so no negative/edge inputs.
template <int N>
static __device__ __forceinline__ v4f rotr4(v4f x) {
    constexpr float SHL = (float)(1ULL << (64 - N));  // 2^(64-N), exact
    constexpr float SHR = 1.0f / (float)(1ULL << N);  // 2^-N, exact
    v4f c = x * SHL;               // exact
    v4f sl = vfract(c);            // exact fract
    v4f s = vfma(x, sp(SHR), sl);  // x*SHR exact => fma == mul-then-add
    return vfract(s);              // exact fract
}

#define GFUN(a, b, c, d, x, y)             \
    do {                                   \
        v##a = soft_add4(v##a, v##b);      \
        v##a = soft_add4(v##a, (x));       \
        v##d = soft_xor4(v##d, v##a);      \
        v##d = rotr4<32>(v##d);            \
        v##c = soft_add4(v##c, v##d);      \
        v##b = soft_xor4(v##b, v##c);      \
        v##b = rotr4<24>(v##b);            \
        v##a = soft_add4(v##a, v##b);      \
        v##a = soft_add4(v##a, (y));       \
        v##d = soft_xor4(v##d, v##a);      \
        v##d = rotr4<16>(v##d);            \
        v##c = soft_add4(v##c, v##d);      \
        v##b = soft_xor4(v##b, v##c);      \
        v##b = rotr4<63>(v##b);            \
    } while (0)

__global__ __launch_bounds__(128, 3) void blake_soft_kernel(
    const float* __restrict__ msg, float* __restrict__ out, int batch) {
    int p = blockIdx.x * blockDim.x + threadIdx.x;
    int i0 = 4 * p;
    if (i0 >= batch) return;
    // batch = 2e6 is a multiple of 4; clamp guards keep generic safety.
    int i1 = (i0 + 1 < batch) ? i0 + 1 : i0;
    int i2 = (i0 + 2 < batch) ? i0 + 2 : i0;
    int i3 = (i0 + 3 < batch) ? i0 + 3 : i0;

    const float4* mp = reinterpret_cast<const float4*>(msg);
    const float4* ra = mp + (size_t)i0 * 4;
    const float4* rb = mp + (size_t)i1 * 4;
    const float4* rc = mp + (size_t)i2 * 4;
    const float4* rd = mp + (size_t)i3 * 4;
    float4 a0 = ra[0], a1 = ra[1], a2 = ra[2], a3 = ra[3];
    float4 b0 = rb[0], b1 = rb[1], b2 = rb[2], b3 = rb[3];
    float4 c0 = rc[0], c1 = rc[1], c2 = rc[2], c3 = rc[3];
    float4 d0 = rd[0], d1 = rd[1], d2 = rd[2], d3 = rd[3];

    v4f m0 = {a0.x, b0.x, c0.x, d0.x}, m1 = {a0.y, b0.y, c0.y, d0.y};
    v4f m2 = {a0.z, b0.z, c0.z, d0.z}, m3 = {a0.w, b0.w, c0.w, d0.w};
    v4f m4 = {a1.x, b1.x, c1.x, d1.x}, m5 = {a1.y, b1.y, c1.y, d1.y};
    v4f m6 = {a1.z, b1.z, c1.z, d1.z}, m7 = {a1.w, b1.w, c1.w, d1.w};
    v4f m8 = {a2.x, b2.x, c2.x, d2.x}, m9 = {a2.y, b2.y, c2.y, d2.y};
    v4f m10 = {a2.z, b2.z, c2.z, d2.z}, m11 = {a2.w, b2.w, c2.w, d2.w};
    v4f m12 = {a3.x, b3.x, c3.x, d3.x}, m13 = {a3.y, b3.y, c3.y, d3.y};
    v4f m14 = {a3.z, b3.z, c3.z, d3.z}, m15 = {a3.w, b3.w, c3.w, d3.w};

    v4f s0 = sp(IV0), s1 = sp(IV1), s2 = sp(IV2), s3 = sp(IV3);
    v4f s4 = sp(IV4), s5 = sp(IV5), s6 = sp(IV6), s7 = sp(IV7);

#pragma unroll 1  // rounds are serial; keep I-cache footprint small
    for (int r = 0; r < 10; ++r) {
        v4f v0 = s0, v1 = s1, v2 = s2, v3 = s3;
        v4f v4 = s4, v5 = s5, v6 = s6, v7 = s7;
        v4f v8 = sp(IV0), v9 = sp(IV1), v10 = sp(IV2), v11 = sp(IV3);
        v4f v12 = sp(IV4), v13 = sp(IV5), v14 = sp(IV6), v15 = sp(IV7);

        GFUN(0, 4, 8, 12, m0, m1);
        GFUN(1, 5, 9, 13, m2, m3);
        GFUN(2, 6, 10, 14, m4, m5);
        GFUN(3, 7, 11, 15, m6, m7);
        GFUN(0, 5, 10, 15, m8, m9);
        GFUN(1, 6, 11, 12, m10, m11);
        GFUN(2, 7, 8, 13, m12, m13);
        GFUN(3, 4, 9, 14, m14, m15);

        s0 = soft_xor4(v0, v8);
        s1 = soft_xor4(v1, v9);
        s2 = soft_xor4(v2, v10);
        s3 = soft_xor4(v3, v11);
        s4 = soft_xor4(v4, v12);
        s5 = soft_xor4(v5, v13);
        s6 = soft_xor4(v6, v14);
        s7 = soft_xor4(v7, v15);
    }

    float4* op = reinterpret_cast<float4*>(out);
    op[(size_t)i0 * 2 + 0] = (float4){s0.x, s1.x, s2.x, s3.x};
    op[(size_t)i0 * 2 + 1] = (float4){s4.x, s5.x, s6.x, s7.x};
    if (i1 != i0) {
        op[(size_t)i1 * 2 + 0] = (float4){s0.y, s1.y, s2.y, s3.y};
        op[(size_t)i1 * 2 + 1] = (float4){s4.y, s5.y, s6.y, s7.y};
    }
    if (i2 != i0) {
        op[(size_t)i2 * 2 + 0] = (float4){s0.z, s1.z, s2.z, s3.z};
        op[(size_t)i2 * 2 + 1] = (float4){s4.z, s5.z, s6.z, s7.z};
    }
    if (i3 != i0) {
        op[(size_t)i3 * 2 + 0] = (float4){s0.w, s1.w, s2.w, s3.w};
        op[(size_t)i3 * 2 + 1] = (float4){s4.w, s5.w, s6.w, s7.w};
    }
}

extern "C" void kernel_launch(void* const* d_in, const int* in_sizes, int n_in,
                              void* d_out, int out_size, void* d_ws, size_t ws_size,
                              hipStream_t stream) {
    (void)n_in;
    (void)out_size;
    (void)d_ws;
    (void)ws_size;
    const float* msg = (const float*)d_in[0];
    float* out = (float*)d_out;
    int batch = in_sizes[0] / 16;
    int quads = (batch + 3) / 4;
    int block = 128;
    int grid = (quads + block - 1) / block;
    blake_soft_kernel<<<grid, block, 0, stream>>>(msg, out, batch);
}

// Round 6
// 1044.196 us; speedup vs baseline: 1.0028x; 1.0028x over previous
//
#include <hip/hip_runtime.h>

// Soft-Blake2 cipher: 2e6 rows x 16 f32 -> 2e6 x 8 f32.
// R10: v4f (4 rows/thread, ILP=2 per sigmoid chain) — R9's plan with the
// CORRECT allocator knob: __attribute__((amdgpu_waves_per_eu(3,3))).
//   R9 post-mortem: __launch_bounds__(128,3) only raises the occupancy
//   FLOOR; the AMDGPU backend still targets max occupancy on its own.
//   It chose VGPR 84 (= 6 waves/SIMD target) and SPILLED to get there
//   (WRITE 64->133MB, FETCH +59MB scratch), occupancy fell to 29.5%,
//   dur 1031us. Same failure class as R6. Setting waves_per_eu MAX=3
//   clamps the occupancy target itself -> RA takes the full ~170-reg
//   budget, no spill-for-occupancy. Demand ~150 (m 64 + state 64 +
//   temps ~24) < 170.
//   Evidence trail: R5/R7/R8 (v2f): 933-950us, VALUBusy ~88%, VGPR 56,
//   launch-shape and budget hints all dead levers. Busy is dominated by
//   the bit-locked trans ops (v_exp/v_rcp, 2 per sigmoid, 800 sigmoids
//   per element); the ~12% idle is dependency stalls in serial sigmoid
//   chains. ILP=2 per wave is the last untested lever; this round is
//   its clean test. If counters come back clean (no spills) and dur
//   stays ~933, the R7 kernel is the structural roofline.
// R3 lesson stands: ANY 1-ulp sigmoid change fails. Do not touch math.
// Numerics: mechanically widened v2f->v4f, bit-identical per element
// (absmax 0.0078125 expected unchanged).

#pragma clang fp contract(off)  // mul/add must round separately, like numpy

typedef float v4f __attribute__((ext_vector_type(4)));

// IV = float32(uint64) * 2^-64, matching np.asarray(ints, float32)/2.0**64.
#define IV0 ((float)7640891576956012808ULL * 0x1p-64f)
#define IV1 ((float)13503953896175478587ULL * 0x1p-64f)
#define IV2 ((float)4354685564936845355ULL * 0x1p-64f)
#define IV3 ((float)11912009170470909681ULL * 0x1p-64f)
#define IV4 ((float)5840696475078001361ULL * 0x1p-64f)
#define IV5 ((float)11170449401992604703ULL * 0x1p-64f)
#define IV6 ((float)2270897969802886507ULL * 0x1p-64f)
#define IV7 ((float)6620516959819538809ULL * 0x1p-64f)

// log2(e) split: HI = float(log2 e), LO = log2(e) - (double)HI.
#define L2E_HI 0x1.715476p+0f
#define L2E_LO 1.9259630e-8f
// 1.5 * 2^23: RNE magic. t + MAGIC is integer-valued with bits
// 0x4B400000 + rint(t) for |t| < 2^22.
#define RNE_MAGIC 12582912.0f

static __device__ __forceinline__ v4f sp(float x) { return (v4f){x, x, x, x}; }
static __device__ __forceinline__ v4f vfma(v4f a, v4f b, v4f c) {
    return __builtin_elementwise_fma(a, b, c);
}
static __device__ __forceinline__ v4f vfract(v4f a) {
    v4f r;
    r.x = __builtin_amdgcn_fractf(a.x);  // v_fract_f32 = S0 - floor(S0)
    r.y = __builtin_amdgcn_fractf(a.y);
    r.z = __builtin_amdgcn_fractf(a.z);
    r.w = __builtin_amdgcn_fractf(a.w);
    return r;
}

// sigmoid(z) = 1/(1+e^-z). Bit-identical per element to R2/R4/R5:
//   n = rint(w*L2E_HI)  [via RNE magic add]
//   f = fma(w,HI,-n) + w*LO   (exact residual, 2 fma)
//   e = v_exp_f32(f)          (|f| <= 0.5)
//   sc = 2^n bit-constructed from the magic sum's bit pattern (exact:
//        low 9 bits of 0x4B400000 are zero, so (bits<<23)+0x3F800000
//        == (n+127)<<23 mod 2^32)
//   d = fma(e, sc, 1.0)       (product exact, one rounding)
//   rcp + 1 Newton step       (~0.5-1 ulp)
static __device__ __forceinline__ v4f sigf4(v4f z) {
    v4f w = -z;
    v4f t = w * L2E_HI;                        // 2x pk_mul
    v4f tmp = t + sp(RNE_MAGIC);               // 2x pk_add
    v4f n = tmp - sp(RNE_MAGIC);               // 2x pk_add (exact)
    v4f f = vfma(w, sp(L2E_HI), -n);           // 2x pk_fma (exact residual)
    f = vfma(w, sp(L2E_LO), f);                // 2x pk_fma
    v4f e;
    e.x = __builtin_amdgcn_exp2f(f.x);         // 4x v_exp_f32 (trans)
    e.y = __builtin_amdgcn_exp2f(f.y);
    e.z = __builtin_amdgcn_exp2f(f.z);
    e.w = __builtin_amdgcn_exp2f(f.w);
    v4f sc;                                    // 2^n exact: (n+127)<<23
    sc.x = __uint_as_float((__float_as_uint(tmp.x) << 23) + 0x3F800000u);
    sc.y = __uint_as_float((__float_as_uint(tmp.y) << 23) + 0x3F800000u);
    sc.z = __uint_as_float((__float_as_uint(tmp.z) << 23) + 0x3F800000u);
    sc.w = __uint_as_float((__float_as_uint(tmp.w) << 23) + 0x3F800000u);
    v4f d = vfma(e, sc, sp(1.0f));             // 2x pk_fma, one rounding
    v4f q0;
    q0.x = __builtin_amdgcn_rcpf(d.x);         // 4x v_rcp_f32 (trans)
    q0.y = __builtin_amdgcn_rcpf(d.y);
    q0.z = __builtin_amdgcn_rcpf(d.z);
    q0.w = __builtin_amdgcn_rcpf(d.w);
    v4f err = vfma(-d, q0, sp(1.0f));          // 2x pk_fma
    return vfma(q0, err, q0);                  // 2x pk_fma
}

static __device__ __forceinline__ v4f soft_add4(v4f x, v4f y) {
    v4f s = x + y;
    v4f w = sigf4(10.0f * (s - 1.0f));         // sub then mul, ref order
    return s - w;
}

static __device__ __forceinline__ v4f soft_xor4(v4f x, v4f y) {
    v4f xs = sigf4(10.0f * (x - 0.5f));
    v4f ys = sigf4(10.0f * (y - 0.5f));
    v4f t1 = xs * (1.0f - ys);
    v4f t2 = (1.0f - xs) * ys;
    v4f r = (t1 + t2) - t1 * t2;               // contraction off
    r.x = __builtin_amdgcn_fmed3f(r.x, 0.0f, 1.0f);  // clamp, 1 op/elem
    r.y = __builtin_amdgcn_fmed3f(r.y, 0.0f, 1.0f);
    r.z = __builtin_amdgcn_fmed3f(r.z, 0.0f, 1.0f);
    r.w = __builtin_amdgcn_fmed3f(r.w, 0.0f, 1.0f);
    return r;
}

// rotate_right, bit-identical to the reference mod-2^64 chain (exact pow2
// scales; fract exact; the single rounding lands at the same mantissa
// position as the reference's sr+sl add). v_fract == sub-floor here:
// inputs are clamped soft_xor outputs in [0,1] (rotr only ever follows
// soft_xor in G), so no negative/edge inputs.
template <int N>
static __device__ __forceinline__ v4f rotr4(v4f x) {
    constexpr float SHL = (float)(1ULL << (64 - N));  // 2^(64-N), exact
    constexpr float SHR = 1.0f / (float)(1ULL << N);  // 2^-N, exact
    v4f c = x * SHL;               // exact
    v4f sl = vfract(c);            // exact fract
    v4f s = vfma(x, sp(SHR), sl);  // x*SHR exact => fma == mul-then-add
    return vfract(s);              // exact fract
}

#define GFUN(a, b, c, d, x, y)             \
    do {                                   \
        v##a = soft_add4(v##a, v##b);      \
        v##a = soft_add4(v##a, (x));       \
        v##d = soft_xor4(v##d, v##a);      \
        v##d = rotr4<32>(v##d);            \
        v##c = soft_add4(v##c, v##d);      \
        v##b = soft_xor4(v##b, v##c);      \
        v##b = rotr4<24>(v##b);            \
        v##a = soft_add4(v##a, v##b);      \
        v##a = soft_add4(v##a, (y));       \
        v##d = soft_xor4(v##d, v##a);      \
        v##d = rotr4<16>(v##d);            \
        v##c = soft_add4(v##c, v##d);      \
        v##b = soft_xor4(v##b, v##c);      \
        v##b = rotr4<63>(v##b);            \
    } while (0)

__global__ __launch_bounds__(128)
__attribute__((amdgpu_waves_per_eu(3, 3)))  // clamp occupancy TARGET: RA
// gets the full 512/3=170-reg budget and cannot spill-for-occupancy
void blake_soft_kernel(
    const float* __restrict__ msg, float* __restrict__ out, int batch) {
    int p = blockIdx.x * blockDim.x + threadIdx.x;
    int i0 = 4 * p;
    if (i0 >= batch) return;
    // batch = 2e6 is a multiple of 4; clamp guards keep generic safety.
    int i1 = (i0 + 1 < batch) ? i0 + 1 : i0;
    int i2 = (i0 + 2 < batch) ? i0 + 2 : i0;
    int i3 = (i0 + 3 < batch) ? i0 + 3 : i0;

    const float4* mp = reinterpret_cast<const float4*>(msg);
    const float4* ra = mp + (size_t)i0 * 4;
    const float4* rb = mp + (size_t)i1 * 4;
    const float4* rc = mp + (size_t)i2 * 4;
    const float4* rd = mp + (size_t)i3 * 4;
    float4 a0 = ra[0], a1 = ra[1], a2 = ra[2], a3 = ra[3];
    float4 b0 = rb[0], b1 = rb[1], b2 = rb[2], b3 = rb[3];
    float4 c0 = rc[0], c1 = rc[1], c2 = rc[2], c3 = rc[3];
    float4 d0 = rd[0], d1 = rd[1], d2 = rd[2], d3 = rd[3];

    v4f m0 = {a0.x, b0.x, c0.x, d0.x}, m1 = {a0.y, b0.y, c0.y, d0.y};
    v4f m2 = {a0.z, b0.z, c0.z, d0.z}, m3 = {a0.w, b0.w, c0.w, d0.w};
    v4f m4 = {a1.x, b1.x, c1.x, d1.x}, m5 = {a1.y, b1.y, c1.y, d1.y};
    v4f m6 = {a1.z, b1.z, c1.z, d1.z}, m7 = {a1.w, b1.w, c1.w, d1.w};
    v4f m8 = {a2.x, b2.x, c2.x, d2.x}, m9 = {a2.y, b2.y, c2.y, d2.y};
    v4f m10 = {a2.z, b2.z, c2.z, d2.z}, m11 = {a2.w, b2.w, c2.w, d2.w};
    v4f m12 = {a3.x, b3.x, c3.x, d3.x}, m13 = {a3.y, b3.y, c3.y, d3.y};
    v4f m14 = {a3.z, b3.z, c3.z, d3.z}, m15 = {a3.w, b3.w, c3.w, d3.w};

    v4f s0 = sp(IV0), s1 = sp(IV1), s2 = sp(IV2), s3 = sp(IV3);
    v4f s4 = sp(IV4), s5 = sp(IV5), s6 = sp(IV6), s7 = sp(IV7);

#pragma unroll 1  // rounds are serial; keep I-cache footprint small
    for (int r = 0; r < 10; ++r) {
        v4f v0 = s0, v1 = s1, v2 = s2, v3 = s3;
        v4f v4 = s4, v5 = s5, v6 = s6, v7 = s7;
        v4f v8 = sp(IV0), v9 = sp(IV1), v10 = sp(IV2), v11 = sp(IV3);
        v4f v12 = sp(IV4), v13 = sp(IV5), v14 = sp(IV6), v15 = sp(IV7);

        GFUN(0, 4, 8, 12, m0, m1);
        GFUN(1, 5, 9, 13, m2, m3);
        GFUN(2, 6, 10, 14, m4, m5);
        GFUN(3, 7, 11, 15, m6, m7);
        GFUN(0, 5, 10, 15, m8, m9);
        GFUN(1, 6, 11, 12, m10, m11);
        GFUN(2, 7, 8, 13, m12, m13);
        GFUN(3, 4, 9, 14, m14, m15);

        s0 = soft_xor4(v0, v8);
        s1 = soft_xor4(v1, v9);
        s2 = soft_xor4(v2, v10);
        s3 = soft_xor4(v3, v11);
        s4 = soft_xor4(v4, v12);
        s5 = soft_xor4(v5, v13);
        s6 = soft_xor4(v6, v14);
        s7 = soft_xor4(v7, v15);
    }

    float4* op = reinterpret_cast<float4*>(out);
    op[(size_t)i0 * 2 + 0] = (float4){s0.x, s1.x, s2.x, s3.x};
    op[(size_t)i0 * 2 + 1] = (float4){s4.x, s5.x, s6.x, s7.x};
    if (i1 != i0) {
        op[(size_t)i1 * 2 + 0] = (float4){s0.y, s1.y, s2.y, s3.y};
        op[(size_t)i1 * 2 + 1] = (float4){s4.y, s5.y, s6.y, s7.y};
    }
    if (i2 != i0) {
        op[(size_t)i2 * 2 + 0] = (float4){s0.z, s1.z, s2.z, s3.z};
        op[(size_t)i2 * 2 + 1] = (float4){s4.z, s5.z, s6.z, s7.z};
    }
    if (i3 != i0) {
        op[(size_t)i3 * 2 + 0] = (float4){s0.w, s1.w, s2.w, s3.w};
        op[(size_t)i3 * 2 + 1] = (float4){s4.w, s5.w, s6.w, s7.w};
    }
}

extern "C" void kernel_launch(void* const* d_in, const int* in_sizes, int n_in,
                              void* d_out, int out_size, void* d_ws, size_t ws_size,
                              hipStream_t stream) {
    (void)n_in;
    (void)out_size;
    (void)d_ws;
    (void)ws_size;
    const float* msg = (const float*)d_in[0];
    float* out = (float*)d_out;
    int batch = in_sizes[0] / 16;
    int quads = (batch + 3) / 4;
    int block = 128;
    int grid = (quads + block - 1) / block;
    blake_soft_kernel<<<grid, block, 0, stream>>>(msg, out, batch);
}

// Round 7
// 960.095 us; speedup vs baseline: 1.0907x; 1.0876x over previous
//
#include <hip/hip_runtime.h>

// Soft-Blake2 cipher: 2e6 rows x 16 f32 -> 2e6 x 8 f32.
// R11 = R7 RESTORED (best verified: 933us kernel / 962us bench).
// FINAL. Session evidence:
//   - R5: inst-encoding shave (magic-RNE, v_fract, med3) 1044->937. WIN.
//   - R6: bounds(128,8)->VGPR32: spilled (+330MB scratch), 973. FAIL.
//   - R7: block=128, no caps: 933, VGPR 56, clean counters. BEST.
//   - R8: bounds(128,4): no-op (allocator keeps 56). NEUTRAL.
//   - R9: v4f ILP=2 + bounds(128,3): VGPR 84 + spills, 1031. FAIL.
//   - R10: v4f + amdgpu_waves_per_eu(3,3): attribute ignored (VGPR 84,
//     spills persist), 1031. FAIL. ILP lever unreachable from source.
// Roofline accounting (R5/R7 counters, VALUBusy 88-89%, Occ ~41%):
//   per-wave issue = ~42k cy full-rate (v_pk_*, minimal under the
//   bit-identity constraint) + 5120 trans x ~16.5cy = ~127k cy
//   -> 100%-busy floor ~824us; measured 933 = 1.13x. Busy is ~65%
//   v_exp/v_rcp: hardware-fixed rate, count algorithmically locked
//   (absmax sits exactly at the 2^-7 threshold; R3 proved 1-ulp
//   sigmoid drift FAILS -> no approximation path). Remaining ~11%
//   idle resisted all 7 structural levers tried. This is the ceiling.

#pragma clang fp contract(off)  // mul/add must round separately, like numpy

typedef float v2f __attribute__((ext_vector_type(2)));

// IV = float32(uint64) * 2^-64, matching np.asarray(ints, float32)/2.0**64.
#define IV0 ((float)7640891576956012808ULL * 0x1p-64f)
#define IV1 ((float)13503953896175478587ULL * 0x1p-64f)
#define IV2 ((float)4354685564936845355ULL * 0x1p-64f)
#define IV3 ((float)11912009170470909681ULL * 0x1p-64f)
#define IV4 ((float)5840696475078001361ULL * 0x1p-64f)
#define IV5 ((float)11170449401992604703ULL * 0x1p-64f)
#define IV6 ((float)2270897969802886507ULL * 0x1p-64f)
#define IV7 ((float)6620516959819538809ULL * 0x1p-64f)

// log2(e) split: HI = float(log2 e), LO = log2(e) - (double)HI.
#define L2E_HI 0x1.715476p+0f
#define L2E_LO 1.9259630e-8f
// 1.5 * 2^23: RNE magic. t + MAGIC is integer-valued with bits
// 0x4B400000 + rint(t) for |t| < 2^22.
#define RNE_MAGIC 12582912.0f

static __device__ __forceinline__ v2f sp(float x) { return (v2f){x, x}; }
static __device__ __forceinline__ v2f vfma(v2f a, v2f b, v2f c) {
    return __builtin_elementwise_fma(a, b, c);
}
static __device__ __forceinline__ v2f vfract(v2f a) {
    v2f r;
    r.x = __builtin_amdgcn_fractf(a.x);  // v_fract_f32 = S0 - floor(S0)
    r.y = __builtin_amdgcn_fractf(a.y);
    return r;
}

// sigmoid(z) = 1/(1+e^-z). Bit-identical to R2/R4/R5:
//   n = rint(w*L2E_HI)  [via RNE magic add]
//   f = fma(w,HI,-n) + w*LO   (exact residual, 2 fma)
//   e = v_exp_f32(f)          (|f| <= 0.5)
//   sc = 2^n bit-constructed from the magic sum's bit pattern (exact:
//        low 9 bits of 0x4B400000 are zero, so (bits<<23)+0x3F800000
//        == (n+127)<<23 mod 2^32)
//   d = fma(e, sc, 1.0)       (product exact, one rounding)
//   rcp + 1 Newton step       (~0.5-1 ulp)
static __device__ __forceinline__ v2f sigf2(v2f z) {
    v2f w = -z;
    v2f t = w * L2E_HI;                        // pk_mul (neg folded)
    v2f tmp = t + sp(RNE_MAGIC);               // pk_add: bits = 0x4B400000+n
    v2f n = tmp - sp(RNE_MAGIC);               // pk_add: n as float, exact
    v2f f = vfma(w, sp(L2E_HI), -n);           // pk_fma (exact residual)
    f = vfma(w, sp(L2E_LO), f);                // pk_fma
    v2f e;
    e.x = __builtin_amdgcn_exp2f(f.x);         // 2x v_exp_f32 (trans)
    e.y = __builtin_amdgcn_exp2f(f.y);
    v2f sc;                                    // 2^n exact: (n+127)<<23
    sc.x = __uint_as_float((__float_as_uint(tmp.x) << 23) + 0x3F800000u);
    sc.y = __uint_as_float((__float_as_uint(tmp.y) << 23) + 0x3F800000u);
    v2f d = vfma(e, sc, sp(1.0f));             // pk_fma, one rounding
    v2f q0;
    q0.x = __builtin_amdgcn_rcpf(d.x);         // 2x v_rcp_f32 (trans)
    q0.y = __builtin_amdgcn_rcpf(d.y);
    v2f err = vfma(-d, q0, sp(1.0f));          // pk_fma
    return vfma(q0, err, q0);                  // pk_fma
}

static __device__ __forceinline__ v2f soft_add2(v2f x, v2f y) {
    v2f s = x + y;
    v2f w = sigf2(10.0f * (s - 1.0f));         // sub then mul, ref order
    return s - w;
}

static __device__ __forceinline__ v2f soft_xor2(v2f x, v2f y) {
    v2f xs = sigf2(10.0f * (x - 0.5f));
    v2f ys = sigf2(10.0f * (y - 0.5f));
    v2f t1 = xs * (1.0f - ys);
    v2f t2 = (1.0f - xs) * ys;
    v2f r = (t1 + t2) - t1 * t2;               // contraction off
    r.x = __builtin_amdgcn_fmed3f(r.x, 0.0f, 1.0f);  // clamp, 1 op/elem
    r.y = __builtin_amdgcn_fmed3f(r.y, 0.0f, 1.0f);
    return r;
}

// rotate_right, bit-identical to the reference mod-2^64 chain (exact pow2
// scales; fract exact; the single rounding lands at the same mantissa
// position as the reference's sr+sl add). v_fract == sub-floor here:
// inputs are clamped soft_xor outputs in [0,1] (rotr only ever follows
// soft_xor in G), so no negative/edge inputs.
template <int N>
static __device__ __forceinline__ v2f rotr2(v2f x) {
    constexpr float SHL = (float)(1ULL << (64 - N));  // 2^(64-N), exact
    constexpr float SHR = 1.0f / (float)(1ULL << N);  // 2^-N, exact
    v2f c = x * SHL;               // exact
    v2f sl = vfract(c);            // exact fract
    v2f s = vfma(x, sp(SHR), sl);  // x*SHR exact => fma == mul-then-add
    return vfract(s);              // exact fract
}

#define GFUN(a, b, c, d, x, y)             \
    do {                                   \
        v##a = soft_add2(v##a, v##b);      \
        v##a = soft_add2(v##a, (x));       \
        v##d = soft_xor2(v##d, v##a);      \
        v##d = rotr2<32>(v##d);            \
        v##c = soft_add2(v##c, v##d);      \
        v##b = soft_xor2(v##b, v##c);      \
        v##b = rotr2<24>(v##b);            \
        v##a = soft_add2(v##a, v##b);      \
        v##a = soft_add2(v##a, (y));       \
        v##d = soft_xor2(v##d, v##a);      \
        v##d = rotr2<16>(v##d);            \
        v##c = soft_add2(v##c, v##d);      \
        v##b = soft_xor2(v##b, v##c);      \
        v##b = rotr2<63>(v##b);            \
    } while (0)

__global__ __launch_bounds__(128) void blake_soft_kernel(
    const float* __restrict__ msg, float* __restrict__ out, int batch) {
    int p = blockIdx.x * blockDim.x + threadIdx.x;
    int i0 = 2 * p;
    if (i0 >= batch) return;
    int i1 = (i0 + 1 < batch) ? i0 + 1 : i0;  // tail guard (batch is even)

    const float4* mp = reinterpret_cast<const float4*>(msg);
    const float4* ma = mp + (size_t)i0 * 4;
    const float4* mb = mp + (size_t)i1 * 4;
    float4 a0 = ma[0], a1 = ma[1], a2 = ma[2], a3 = ma[3];
    float4 b0 = mb[0], b1 = mb[1], b2 = mb[2], b3 = mb[3];

    v2f m0 = {a0.x, b0.x}, m1 = {a0.y, b0.y}, m2 = {a0.z, b0.z}, m3 = {a0.w, b0.w};
    v2f m4 = {a1.x, b1.x}, m5 = {a1.y, b1.y}, m6 = {a1.z, b1.z}, m7 = {a1.w, b1.w};
    v2f m8 = {a2.x, b2.x}, m9 = {a2.y, b2.y}, m10 = {a2.z, b2.z}, m11 = {a2.w, b2.w};
    v2f m12 = {a3.x, b3.x}, m13 = {a3.y, b3.y}, m14 = {a3.z, b3.z}, m15 = {a3.w, b3.w};

    v2f s0 = sp(IV0), s1 = sp(IV1), s2 = sp(IV2), s3 = sp(IV3);
    v2f s4 = sp(IV4), s5 = sp(IV5), s6 = sp(IV6), s7 = sp(IV7);

#pragma unroll 1  // rounds are serial; keep I-cache footprint small
    for (int r = 0; r < 10; ++r) {
        v2f v0 = s0, v1 = s1, v2 = s2, v3 = s3;
        v2f v4 = s4, v5 = s5, v6 = s6, v7 = s7;
        v2f v8 = sp(IV0), v9 = sp(IV1), v10 = sp(IV2), v11 = sp(IV3);
        v2f v12 = sp(IV4), v13 = sp(IV5), v14 = sp(IV6), v15 = sp(IV7);

        GFUN(0, 4, 8, 12, m0, m1);
        GFUN(1, 5, 9, 13, m2, m3);
        GFUN(2, 6, 10, 14, m4, m5);
        GFUN(3, 7, 11, 15, m6, m7);
        GFUN(0, 5, 10, 15, m8, m9);
        GFUN(1, 6, 11, 12, m10, m11);
        GFUN(2, 7, 8, 13, m12, m13);
        GFUN(3, 4, 9, 14, m14, m15);

        s0 = soft_xor2(v0, v8);
        s1 = soft_xor2(v1, v9);
        s2 = soft_xor2(v2, v10);
        s3 = soft_xor2(v3, v11);
        s4 = soft_xor2(v4, v12);
        s5 = soft_xor2(v5, v13);
        s6 = soft_xor2(v6, v14);
        s7 = soft_xor2(v7, v15);
    }

    float4* op = reinterpret_cast<float4*>(out);
    float4 oa0 = {s0.x, s1.x, s2.x, s3.x};
    float4 oa1 = {s4.x, s5.x, s6.x, s7.x};
    op[(size_t)i0 * 2 + 0] = oa0;
    op[(size_t)i0 * 2 + 1] = oa1;
    if (i1 != i0) {
        float4 ob0 = {s0.y, s1.y, s2.y, s3.y};
        float4 ob1 = {s4.y, s5.y, s6.y, s7.y};
        op[(size_t)i1 * 2 + 0] = ob0;
        op[(size_t)i1 * 2 + 1] = ob1;
    }
}

extern "C" void kernel_launch(void* const* d_in, const int* in_sizes, int n_in,
                              void* d_out, int out_size, void* d_ws, size_t ws_size,
                              hipStream_t stream) {
    (void)n_in;
    (void)out_size;
    (void)d_ws;
    (void)ws_size;
    const float* msg = (const float*)d_in[0];
    float* out = (float*)d_out;
    int batch = in_sizes[0] / 16;
    int pairs = (batch + 1) / 2;
    int block = 128;  // 2-wave WGs: fine-grained residency + drain
    int grid = (pairs + block - 1) / block;
    blake_soft_kernel<<<grid, block, 0, stream>>>(msg, out, batch);
}